// Round 8
// baseline (233.761 us; speedup 1.0000x reference)
//
#include <hip/hip_runtime.h>
#include <math.h>

// CPNet registration: B=8 batches, pc1 (4 x 4096), pc2 (4 x 4096), fp32.
// Outputs: T (8,4,4)=128 | q (8,4)=32 | t (8,3)=24  -> 184 floats concat.
//
// R8: R6 (proven PASS, 142.7us) + ONE change: single-dispatch fan-in.
// Phase 1 = R6's dense two-pass packed softmax verbatim. Last block per
// batch (device-scope atomic counter, zeroed via hipMemsetAsync) runs
// R6's combine/moments/solve bodies for its batch. Sparse pass-2 stays
// quarantined (R4/R5 NaNs); cooperative launch quarantined (R7 no-run).

typedef float v2f __attribute__((ext_vector_type(2)));

constexpr int cB  = 8;
constexpr int cN1 = 4096;
constexpr int cN2 = 4096;
constexpr int cMC = 8;               // m-chunks
constexpr int cCHUNK = cN2 / cMC;    // 512
constexpr int cNB = cN1 / 256;       // 16 n-blocks
constexpr int cBLK = cNB * cMC;      // 128 blocks per batch
constexpr float cEPS  = 1e-5f;
constexpr float cKK   = 0.34657359027997264f;   // ln2/2 = 1/(FACT*log2(e))
constexpr float cEPSK = cEPS * cKK;             // scaled clamp
constexpr float cUNSC = -1.4426950408889634f;   // -1/ln2 (undo -ln2 packing)

// ---------------- workspace layout (bytes) ----------------
// partA : float4[cMC*cB*cN1] @ 0         (4 MiB)
// partM : float [cMC*cB*cN1] @ 0x400000  (1 MiB)
// near4 : float4[cB*cN1]     @ 0x500000  (512 KiB)
// cnt   : uint[cB]           @ 0x580000  (32 B, zeroed each launch)
constexpr size_t OFF_PARTM = 0x400000;
constexpr size_t OFF_NEAR  = 0x500000;
constexpr size_t OFF_CNT   = 0x580000;

// ---------------- batched block reduce (256 thr, 4 waves, doubles) ---------
__device__ __forceinline__ void reduce_multi(double* v, int nv, double* lds,
                                             int tid) {
  const int lane = tid & 63, w = tid >> 6;
  for (int i = 0; i < nv; ++i) {
    double x = v[i];
    for (int s = 32; s > 0; s >>= 1) x += __shfl_xor(x, s, 64);
    if (lane == 0) lds[i * 4 + w] = x;
  }
  __syncthreads();
  if (tid < nv)
    lds[tid * 4] = lds[tid * 4] + lds[tid * 4 + 1] + lds[tid * 4 + 2] +
                   lds[tid * 4 + 3];
  __syncthreads();
  for (int i = 0; i < nv; ++i) v[i] = lds[i * 4];
  __syncthreads();
}

__global__ __launch_bounds__(256) void cpnet_fused(
    const float* __restrict__ pc1, const float* __restrict__ pc2,
    float4* __restrict__ partA, float* __restrict__ partM,
    float4* __restrict__ near4, unsigned int* __restrict__ cnt,
    float* __restrict__ out) {
  __shared__ float xs[cCHUNK], ys[cCHUNK], zs[cCHUNK], ws[cCHUNK];
  __shared__ double lds[32 * 4];
  __shared__ int is_last;
  const int tid = threadIdx.x;
  const int nb = blockIdx.x, c = blockIdx.y, b = blockIdx.z;
  const int n = nb * 256 + tid;

  // =============== phase 1: R6's partial softmax, verbatim ================
  {
    // fused pack: (-ln2*x, -ln2*y, -ln2*z, (ln2/2)*|p|^2)
    const float* p2b = pc2 + (size_t)b * 4 * cN2 + c * cCHUNK;
    for (int i = tid; i < cCHUNK; i += 256) {
      float x = p2b[i], y = p2b[cN2 + i], z = p2b[2 * cN2 + i];
      xs[i] = -2.0f * cKK * x;
      ys[i] = -2.0f * cKK * y;
      zs[i] = -2.0f * cKK * z;
      ws[i] = cKK * (x * x + y * y + z * z);
    }
    __syncthreads();

    const float* p1b = pc1 + (size_t)b * 4 * cN1;
    const float x1 = p1b[n], y1 = p1b[cN1 + n], z1 = p1b[2 * cN1 + n];
    const float n1k = cKK * (x1 * x1 + y1 * y1 + z1 * z1);
    const v2f X1 = {x1, x1}, Y1 = {y1, y1}, Z1 = {z1, z1}, N1K = {n1k, n1k};

    const v2f* xs2 = (const v2f*)xs;
    const v2f* ys2 = (const v2f*)ys;
    const v2f* zs2 = (const v2f*)zs;
    const v2f* ws2 = (const v2f*)ws;

    // pass 1: min dk over chunk (dk = (ln2/2)*d; s2 = rcp(dk) monotone dec.)
    v2f dmin2 = {3.0e38f, 3.0e38f};
#pragma unroll 4
    for (int m = 0; m < cCHUNK / 2; ++m) {
      v2f dk = X1 * xs2[m] + (Y1 * ys2[m] + (Z1 * zs2[m] + (ws2[m] + N1K)));
      dmin2 = __builtin_elementwise_min(dmin2, dk);
    }
    const float dmin = fminf(dmin2.x, dmin2.y);
    const float M = __builtin_amdgcn_rcpf(fmaxf(dmin, cEPSK));
    const v2f M2 = {M, M};
    const v2f EPS2 = {cEPSK, cEPSK};

    // pass 2: exp-sum + weighted accumulators, e = exp2(s2 - M) <= 1
    v2f S2 = {0.f, 0.f}, Ax2 = {0.f, 0.f}, Ay2 = {0.f, 0.f}, Az2 = {0.f, 0.f};
#pragma unroll 4
    for (int m = 0; m < cCHUNK / 2; ++m) {
      v2f vx = xs2[m], vy = ys2[m], vz = zs2[m];
      v2f dk = X1 * vx + (Y1 * vy + (Z1 * vz + (ws2[m] + N1K)));
      dk = __builtin_elementwise_max(dk, EPS2);
      v2f s2v;
      s2v.x = __builtin_amdgcn_rcpf(dk.x);
      s2v.y = __builtin_amdgcn_rcpf(dk.y);
      v2f d2 = s2v - M2;
      v2f e;
      e.x = __builtin_amdgcn_exp2f(d2.x);
      e.y = __builtin_amdgcn_exp2f(d2.y);
      S2 += e;
      Ax2 += e * vx;
      Ay2 += e * vy;
      Az2 += e * vz;
    }

    const int idx = (c * cB + b) * cN1 + n;
    partA[idx] = make_float4(Ax2.x + Ax2.y, Ay2.x + Ay2.y, Az2.x + Az2.y,
                             S2.x + S2.y);
    partM[idx] = M;
  }

  // =============== fan-in: last block of batch b finalizes =================
  __threadfence();   // release: publish this block's partials
  if (tid == 0)
    is_last = (atomicAdd(&cnt[b], 1u) == (unsigned)(cBLK - 1));
  __syncthreads();
  if (!is_last) return;
  __threadfence();   // acquire: observe all batch-b partials

  const float* p1b = pc1 + (size_t)b * 4 * cN1;

  // ---- combine (R6 K2 body over all 4096 rows) ----
  double acc[23];
  acc[0] = 0.0;
  for (int n2 = tid; n2 < cN1; n2 += 256) {
    float Ms[cMC];
    float g = -3.0e38f;
#pragma unroll
    for (int c2 = 0; c2 < cMC; ++c2) {
      Ms[c2] = partM[(c2 * cB + b) * cN1 + n2];
      g = fmaxf(g, Ms[c2]);
    }
    float S = 0.f, nx = 0.f, ny = 0.f, nz = 0.f;
#pragma unroll
    for (int c2 = 0; c2 < cMC; ++c2) {
      float w = exp2f(Ms[c2] - g);
      float4 a = partA[(c2 * cB + b) * cN1 + n2];
      S += a.w * w; nx += a.x * w; ny += a.y * w; nz += a.z * w;
    }
    float inv = cUNSC / S;       // undo -ln2 packing + softmax normalize
    nx *= inv; ny *= inv; nz *= inv;
    float xx1 = p1b[n2], yy1 = p1b[cN1 + n2], zz1 = p1b[2 * cN1 + n2];
    float dx = xx1 - nx, dy = yy1 - ny, dz = zz1 - nz;
    float dist = sqrtf(dx * dx + dy * dy + dz * dz);
    near4[b * cN1 + n2] = make_float4(nx, ny, nz, dist);
    acc[0] += (double)dist;
  }
  reduce_multi(acc, 1, lds, tid);
  const float meanf = (float)(acc[0] / (double)cN1);

  // ---- moments (R6 K3 body) ----
  for (int i = 0; i < 23; ++i) acc[i] = 0.0;
  for (int n2 = tid; n2 < cN1; n2 += 256) {
    float4 nn = near4[b * cN1 + n2];
    float u = (nn.w - meanf - cEPS) * 1e10f;
    float ind = 1.0f / (1.0f + expf(u));
    double di = (double)ind, di2 = di * di;
    double x1 = (double)p1b[n2], y1 = (double)p1b[cN1 + n2],
           z1 = (double)p1b[2 * cN1 + n2];
    double x2 = (double)nn.x, y2 = (double)nn.y, z2 = (double)nn.z;
    acc[0] += di;
    acc[1] += di * x1;  acc[2] += di * y1;  acc[3] += di * z1;
    acc[4] += di * x2;  acc[5] += di * y2;  acc[6] += di * z2;
    acc[7] += di2;
    acc[8]  += di2 * x1;  acc[9]  += di2 * y1;  acc[10] += di2 * z1;
    acc[11] += di2 * x2;  acc[12] += di2 * y2;  acc[13] += di2 * z2;
    acc[14] += di2 * x1 * x2; acc[15] += di2 * x1 * y2; acc[16] += di2 * x1 * z2;
    acc[17] += di2 * y1 * x2; acc[18] += di2 * y1 * y2; acc[19] += di2 * y1 * z2;
    acc[20] += di2 * z1 * x2; acc[21] += di2 * z1 * y2; acc[22] += di2 * z1 * z2;
  }
  reduce_multi(acc, 23, lds, tid);

  // ---- solve (R6 K4 body) ----
  if (tid == 0) {
    double W = acc[0];
    double c1[3] = {acc[1] / W, acc[2] / W, acc[3] / W};
    double c2[3] = {acc[4] / W, acc[5] / W, acc[6] / W};
    double H[3][3];
    for (int i = 0; i < 3; ++i)
      for (int j = 0; j < 3; ++j)
        H[i][j] = acc[14 + 3 * i + j] - c2[j] * acc[8 + i] -
                  c1[i] * acc[11 + j] + c1[i] * c2[j] * acc[7];

    // Horn / Besl-McKay 4x4 quaternion matrix -> Jacobi eigen (6 sweeps)
    double trH = H[0][0] + H[1][1] + H[2][2];
    double Nm[4][4], V[4][4];
    Nm[0][0] = trH;
    Nm[0][1] = Nm[1][0] = H[1][2] - H[2][1];
    Nm[0][2] = Nm[2][0] = H[2][0] - H[0][2];
    Nm[0][3] = Nm[3][0] = H[0][1] - H[1][0];
    Nm[1][1] = 2.0 * H[0][0] - trH;
    Nm[1][2] = Nm[2][1] = H[0][1] + H[1][0];
    Nm[1][3] = Nm[3][1] = H[0][2] + H[2][0];
    Nm[2][2] = 2.0 * H[1][1] - trH;
    Nm[2][3] = Nm[3][2] = H[1][2] + H[2][1];
    Nm[3][3] = 2.0 * H[2][2] - trH;

    for (int i = 0; i < 4; ++i)
      for (int j = 0; j < 4; ++j) V[i][j] = (i == j) ? 1.0 : 0.0;

    for (int sweep = 0; sweep < 6; ++sweep) {
      for (int p = 0; p < 3; ++p) {
        for (int q = p + 1; q < 4; ++q) {
          double apq = Nm[p][q];
          if (fabs(apq) < 1e-300) continue;
          double theta = (Nm[q][q] - Nm[p][p]) / (2.0 * apq);
          double tt = (theta >= 0.0 ? 1.0 : -1.0) /
                      (fabs(theta) + sqrt(theta * theta + 1.0));
          double cc = 1.0 / sqrt(tt * tt + 1.0);
          double ss = tt * cc;
          for (int k = 0; k < 4; ++k) {
            double akp = Nm[k][p], akq = Nm[k][q];
            Nm[k][p] = cc * akp - ss * akq;
            Nm[k][q] = ss * akp + cc * akq;
          }
          for (int k = 0; k < 4; ++k) {
            double apk = Nm[p][k], aqk = Nm[q][k];
            Nm[p][k] = cc * apk - ss * aqk;
            Nm[q][k] = ss * apk + cc * aqk;
          }
          for (int k = 0; k < 4; ++k) {
            double vkp = V[k][p], vkq = V[k][q];
            V[k][p] = cc * vkp - ss * vkq;
            V[k][q] = ss * vkp + cc * vkq;
          }
        }
      }
    }
    int imax = 0;
    for (int i = 1; i < 4; ++i)
      if (Nm[i][i] > Nm[imax][imax]) imax = i;
    double qw = V[0][imax], qx = V[1][imax], qy = V[2][imax], qz = V[3][imax];
    double qn = sqrt(qw * qw + qx * qx + qy * qy + qz * qz);
    qw /= qn; qx /= qn; qy /= qn; qz /= qn;

    double R[3][3];
    R[0][0] = 1.0 - 2.0 * (qy * qy + qz * qz);
    R[0][1] = 2.0 * (qx * qy - qw * qz);
    R[0][2] = 2.0 * (qx * qz + qw * qy);
    R[1][0] = 2.0 * (qx * qy + qw * qz);
    R[1][1] = 1.0 - 2.0 * (qx * qx + qz * qz);
    R[1][2] = 2.0 * (qy * qz - qw * qx);
    R[2][0] = 2.0 * (qx * qz - qw * qy);
    R[2][1] = 2.0 * (qy * qz + qw * qx);
    R[2][2] = 1.0 - 2.0 * (qx * qx + qy * qy);

    // safeguard vs convention flip: objective is tr(R H); transpose if better
    double tr1 = 0.0, tr2 = 0.0;
    for (int i = 0; i < 3; ++i)
      for (int j = 0; j < 3; ++j) {
        tr1 += R[i][j] * H[j][i];
        tr2 += R[j][i] * H[j][i];
      }
    if (tr2 > tr1) {
      for (int i = 0; i < 3; ++i)
        for (int j = i + 1; j < 3; ++j) {
          double tmp = R[i][j]; R[i][j] = R[j][i]; R[j][i] = tmp;
        }
    }

    double tx = c2[0] - (R[0][0] * c1[0] + R[0][1] * c1[1] + R[0][2] * c1[2]);
    double ty = c2[1] - (R[1][0] * c1[0] + R[1][1] * c1[1] + R[1][2] * c1[2]);
    double tz = c2[2] - (R[2][0] * c1[0] + R[2][1] * c1[1] + R[2][2] * c1[2]);

    auto sgn = [](double x) { return x >= 0.0 ? 1.0 : -1.0; };
    double oqw = 0.5 * sqrt(fmax(1.0 + R[0][0] + R[1][1] + R[2][2], 1e-12));
    double oqx = 0.5 * sqrt(fmax(1.0 + R[0][0] - R[1][1] - R[2][2], 1e-12)) *
                 sgn(R[2][1] - R[1][2]);
    double oqy = 0.5 * sqrt(fmax(1.0 - R[0][0] + R[1][1] - R[2][2], 1e-12)) *
                 sgn(R[0][2] - R[2][0]);
    double oqz = 0.5 * sqrt(fmax(1.0 - R[0][0] - R[1][1] + R[2][2], 1e-12)) *
                 sgn(R[1][0] - R[0][1]);

    float* T = out + b * 16;
    T[0]  = (float)R[0][0]; T[1]  = (float)R[0][1]; T[2]  = (float)R[0][2]; T[3]  = (float)tx;
    T[4]  = (float)R[1][0]; T[5]  = (float)R[1][1]; T[6]  = (float)R[1][2]; T[7]  = (float)ty;
    T[8]  = (float)R[2][0]; T[9]  = (float)R[2][1]; T[10] = (float)R[2][2]; T[11] = (float)tz;
    T[12] = 0.f; T[13] = 0.f; T[14] = 0.f; T[15] = 1.f;
    float* Q = out + 128 + b * 4;
    Q[0] = (float)oqw; Q[1] = (float)oqx; Q[2] = (float)oqy; Q[3] = (float)oqz;
    float* Tt = out + 160 + b * 3;
    Tt[0] = (float)tx; Tt[1] = (float)ty; Tt[2] = (float)tz;
  }
}

// ---------------- launch ----------------
extern "C" void kernel_launch(void* const* d_in, const int* in_sizes, int n_in,
                              void* d_out, int out_size, void* d_ws, size_t ws_size,
                              hipStream_t stream) {
  const float* pc1 = (const float*)d_in[0];
  const float* pc2 = (const float*)d_in[1];
  float* out = (float*)d_out;
  char* ws = (char*)d_ws;

  float4* partA = (float4*)ws;
  float*  partM = (float*)(ws + OFF_PARTM);
  float4* near4 = (float4*)(ws + OFF_NEAR);
  unsigned int* cnt = (unsigned int*)(ws + OFF_CNT);

  hipMemsetAsync(cnt, 0, cB * sizeof(unsigned int), stream);
  cpnet_fused<<<dim3(cNB, cMC, cB), 256, 0, stream>>>(pc1, pc2, partA, partM,
                                                      near4, cnt, out);
}

// Round 9
// 145.046 us; speedup vs baseline: 1.6116x; 1.6116x over previous
//
#include <hip/hip_runtime.h>
#include <math.h>

// CPNet registration: B=8 batches, pc1 (4 x 4096), pc2 (4 x 4096), fp32.
// Outputs: T (8,4,4)=128 | q (8,4)=32 | t (8,3)=24  -> 184 floats concat.
//
// R9: R6's proven math, 2 dispatches instead of 4. K1 = R6 partial
// verbatim (1024 blocks). K2 = per-batch finalize: 8 blocks x 512
// threads, 8 rows/thread, combine kept in REGISTERS (no near4 global
// round-trip), mean + 23 fp64 moments via block reduction, Kabsch solve
// on tid 0. Quarantined (measured failures): sparse pass-2 (R4/R5 NaN),
// cooperative launch (R7 never ran), atomic fan-in + threadfence (R8:
// L2-writeback storm, 22% VALUBusy, +91us).

typedef float v2f __attribute__((ext_vector_type(2)));

constexpr int cB  = 8;
constexpr int cN1 = 4096;
constexpr int cN2 = 4096;
constexpr int cMC = 8;               // m-chunks
constexpr int cCHUNK = cN2 / cMC;    // 512
constexpr int cROWS = cN1 / 512;     // 8 rows per finalize thread
constexpr float cEPS  = 1e-5f;
constexpr float cKK   = 0.34657359027997264f;   // ln2/2 = 1/(FACT*log2(e))
constexpr float cEPSK = cEPS * cKK;             // scaled clamp
constexpr float cUNSC = -1.4426950408889634f;   // -1/ln2 (undo -ln2 packing)

// ---------------- workspace layout (bytes) ----------------
// partA : float4[cMC*cB*cN1] @ 0         (4 MiB)
// partM : float [cMC*cB*cN1] @ 0x400000  (1 MiB)
constexpr size_t OFF_PARTM = 0x400000;

// ============ K1: R6's proven two-pass packed softmax partials =============
__global__ __launch_bounds__(256) void cpnet_partial(
    const float* __restrict__ pc1, const float* __restrict__ pc2,
    float4* __restrict__ partA, float* __restrict__ partM) {
  __shared__ float xs[cCHUNK], ys[cCHUNK], zs[cCHUNK], ws[cCHUNK];
  const int tid = threadIdx.x;
  const int b = blockIdx.z, c = blockIdx.y;
  const int n = blockIdx.x * 256 + tid;

  // fused pack: (-ln2*x, -ln2*y, -ln2*z, (ln2/2)*|p|^2)
  const float* p2b = pc2 + (size_t)b * 4 * cN2 + c * cCHUNK;
  for (int i = tid; i < cCHUNK; i += 256) {
    float x = p2b[i], y = p2b[cN2 + i], z = p2b[2 * cN2 + i];
    xs[i] = -2.0f * cKK * x;
    ys[i] = -2.0f * cKK * y;
    zs[i] = -2.0f * cKK * z;
    ws[i] = cKK * (x * x + y * y + z * z);
  }
  __syncthreads();

  const float* p1b = pc1 + (size_t)b * 4 * cN1;
  const float x1 = p1b[n], y1 = p1b[cN1 + n], z1 = p1b[2 * cN1 + n];
  const float n1k = cKK * (x1 * x1 + y1 * y1 + z1 * z1);
  const v2f X1 = {x1, x1}, Y1 = {y1, y1}, Z1 = {z1, z1}, N1K = {n1k, n1k};

  const v2f* xs2 = (const v2f*)xs;
  const v2f* ys2 = (const v2f*)ys;
  const v2f* zs2 = (const v2f*)zs;
  const v2f* ws2 = (const v2f*)ws;

  // pass 1: min dk over chunk (dk = (ln2/2)*d; s2 = rcp(dk) monotone dec.)
  v2f dmin2 = {3.0e38f, 3.0e38f};
#pragma unroll 4
  for (int m = 0; m < cCHUNK / 2; ++m) {
    v2f dk = X1 * xs2[m] + (Y1 * ys2[m] + (Z1 * zs2[m] + (ws2[m] + N1K)));
    dmin2 = __builtin_elementwise_min(dmin2, dk);
  }
  const float dmin = fminf(dmin2.x, dmin2.y);
  const float M = __builtin_amdgcn_rcpf(fmaxf(dmin, cEPSK));
  const v2f M2 = {M, M};
  const v2f EPS2 = {cEPSK, cEPSK};

  // pass 2: exp-sum + weighted accumulators, e = exp2(s2 - M) <= 1
  v2f S2 = {0.f, 0.f}, Ax2 = {0.f, 0.f}, Ay2 = {0.f, 0.f}, Az2 = {0.f, 0.f};
#pragma unroll 4
  for (int m = 0; m < cCHUNK / 2; ++m) {
    v2f vx = xs2[m], vy = ys2[m], vz = zs2[m];
    v2f dk = X1 * vx + (Y1 * vy + (Z1 * vz + (ws2[m] + N1K)));
    dk = __builtin_elementwise_max(dk, EPS2);
    v2f s2v;
    s2v.x = __builtin_amdgcn_rcpf(dk.x);
    s2v.y = __builtin_amdgcn_rcpf(dk.y);
    v2f d2 = s2v - M2;
    v2f e;
    e.x = __builtin_amdgcn_exp2f(d2.x);
    e.y = __builtin_amdgcn_exp2f(d2.y);
    S2 += e;
    Ax2 += e * vx;
    Ay2 += e * vy;
    Az2 += e * vz;
  }

  const int idx = (c * cB + b) * cN1 + n;
  partA[idx] = make_float4(Ax2.x + Ax2.y, Ay2.x + Ay2.y, Az2.x + Az2.y,
                           S2.x + S2.y);
  partM[idx] = M;
}

// ---------------- batched block reduce (512 thr, 8 waves, doubles) ---------
__device__ __forceinline__ void reduce_multi(double* v, int nv, double* lds,
                                             int tid) {
  const int lane = tid & 63, w = tid >> 6;   // 8 waves
  for (int i = 0; i < nv; ++i) {
    double x = v[i];
    for (int s = 32; s > 0; s >>= 1) x += __shfl_xor(x, s, 64);
    if (lane == 0) lds[i * 8 + w] = x;
  }
  __syncthreads();
  if (tid < nv) {
    double s = 0.0;
    for (int k = 0; k < 8; ++k) s += lds[tid * 8 + k];
    lds[tid * 8] = s;
  }
  __syncthreads();
  for (int i = 0; i < nv; ++i) v[i] = lds[i * 8];
  __syncthreads();
}

// ============ K2: per-batch finalize: combine(reg) + moments + solve =======
__global__ __launch_bounds__(512) void cpnet_finalize(
    const float* __restrict__ pc1,
    const float4* __restrict__ partA, const float* __restrict__ partM,
    float* __restrict__ out) {
  __shared__ double lds[23 * 8];
  const int b = blockIdx.x, tid = threadIdx.x;
  const float* p1b = pc1 + (size_t)b * 4 * cN1;

  // ---- combine (R6 K2 math), results held in registers ----
  float rx[cROWS], ry[cROWS], rz[cROWS], rd[cROWS];
  float px[cROWS], py[cROWS], pz[cROWS];
  double acc[23];
  acc[0] = 0.0;
#pragma unroll
  for (int k = 0; k < cROWS; ++k) {
    const int n = k * 512 + tid;
    float Ms[cMC];
    float g = -3.0e38f;
#pragma unroll
    for (int c = 0; c < cMC; ++c) {
      Ms[c] = partM[(c * cB + b) * cN1 + n];
      g = fmaxf(g, Ms[c]);
    }
    float S = 0.f, nx = 0.f, ny = 0.f, nz = 0.f;
#pragma unroll
    for (int c = 0; c < cMC; ++c) {
      float w = exp2f(Ms[c] - g);
      float4 a = partA[(c * cB + b) * cN1 + n];
      S += a.w * w; nx += a.x * w; ny += a.y * w; nz += a.z * w;
    }
    float inv = cUNSC / S;       // undo -ln2 packing + softmax normalize
    nx *= inv; ny *= inv; nz *= inv;
    float xx1 = p1b[n], yy1 = p1b[cN1 + n], zz1 = p1b[2 * cN1 + n];
    float dx = xx1 - nx, dy = yy1 - ny, dz = zz1 - nz;
    float dist = sqrtf(dx * dx + dy * dy + dz * dz);
    rx[k] = nx; ry[k] = ny; rz[k] = nz; rd[k] = dist;
    px[k] = xx1; py[k] = yy1; pz[k] = zz1;
    acc[0] += (double)dist;
  }
  reduce_multi(acc, 1, lds, tid);
  const float meanf = (float)(acc[0] / (double)cN1);

  // ---- moments (R6 K3 math) from registers ----
  for (int i = 0; i < 23; ++i) acc[i] = 0.0;
#pragma unroll
  for (int k = 0; k < cROWS; ++k) {
    float u = (rd[k] - meanf - cEPS) * 1e10f;
    float ind = 1.0f / (1.0f + expf(u));
    double di = (double)ind, di2 = di * di;
    double x1 = (double)px[k], y1 = (double)py[k], z1 = (double)pz[k];
    double x2 = (double)rx[k], y2 = (double)ry[k], z2 = (double)rz[k];
    acc[0] += di;
    acc[1] += di * x1;  acc[2] += di * y1;  acc[3] += di * z1;
    acc[4] += di * x2;  acc[5] += di * y2;  acc[6] += di * z2;
    acc[7] += di2;
    acc[8]  += di2 * x1;  acc[9]  += di2 * y1;  acc[10] += di2 * z1;
    acc[11] += di2 * x2;  acc[12] += di2 * y2;  acc[13] += di2 * z2;
    acc[14] += di2 * x1 * x2; acc[15] += di2 * x1 * y2; acc[16] += di2 * x1 * z2;
    acc[17] += di2 * y1 * x2; acc[18] += di2 * y1 * y2; acc[19] += di2 * y1 * z2;
    acc[20] += di2 * z1 * x2; acc[21] += di2 * z1 * y2; acc[22] += di2 * z1 * z2;
  }
  reduce_multi(acc, 23, lds, tid);

  // ---- solve (R6 K4 body verbatim) ----
  if (tid == 0) {
    double W = acc[0];
    double c1[3] = {acc[1] / W, acc[2] / W, acc[3] / W};
    double c2[3] = {acc[4] / W, acc[5] / W, acc[6] / W};
    double H[3][3];
    for (int i = 0; i < 3; ++i)
      for (int j = 0; j < 3; ++j)
        H[i][j] = acc[14 + 3 * i + j] - c2[j] * acc[8 + i] -
                  c1[i] * acc[11 + j] + c1[i] * c2[j] * acc[7];

    // Horn / Besl-McKay 4x4 quaternion matrix -> Jacobi eigen (6 sweeps)
    double trH = H[0][0] + H[1][1] + H[2][2];
    double Nm[4][4], V[4][4];
    Nm[0][0] = trH;
    Nm[0][1] = Nm[1][0] = H[1][2] - H[2][1];
    Nm[0][2] = Nm[2][0] = H[2][0] - H[0][2];
    Nm[0][3] = Nm[3][0] = H[0][1] - H[1][0];
    Nm[1][1] = 2.0 * H[0][0] - trH;
    Nm[1][2] = Nm[2][1] = H[0][1] + H[1][0];
    Nm[1][3] = Nm[3][1] = H[0][2] + H[2][0];
    Nm[2][2] = 2.0 * H[1][1] - trH;
    Nm[2][3] = Nm[3][2] = H[1][2] + H[2][1];
    Nm[3][3] = 2.0 * H[2][2] - trH;

    for (int i = 0; i < 4; ++i)
      for (int j = 0; j < 4; ++j) V[i][j] = (i == j) ? 1.0 : 0.0;

    for (int sweep = 0; sweep < 6; ++sweep) {
      for (int p = 0; p < 3; ++p) {
        for (int q = p + 1; q < 4; ++q) {
          double apq = Nm[p][q];
          if (fabs(apq) < 1e-300) continue;
          double theta = (Nm[q][q] - Nm[p][p]) / (2.0 * apq);
          double tt = (theta >= 0.0 ? 1.0 : -1.0) /
                      (fabs(theta) + sqrt(theta * theta + 1.0));
          double cc = 1.0 / sqrt(tt * tt + 1.0);
          double ss = tt * cc;
          for (int k = 0; k < 4; ++k) {
            double akp = Nm[k][p], akq = Nm[k][q];
            Nm[k][p] = cc * akp - ss * akq;
            Nm[k][q] = ss * akp + cc * akq;
          }
          for (int k = 0; k < 4; ++k) {
            double apk = Nm[p][k], aqk = Nm[q][k];
            Nm[p][k] = cc * apk - ss * aqk;
            Nm[q][k] = ss * apk + cc * aqk;
          }
          for (int k = 0; k < 4; ++k) {
            double vkp = V[k][p], vkq = V[k][q];
            V[k][p] = cc * vkp - ss * vkq;
            V[k][q] = ss * vkp + cc * vkq;
          }
        }
      }
    }
    int imax = 0;
    for (int i = 1; i < 4; ++i)
      if (Nm[i][i] > Nm[imax][imax]) imax = i;
    double qw = V[0][imax], qx = V[1][imax], qy = V[2][imax], qz = V[3][imax];
    double qn = sqrt(qw * qw + qx * qx + qy * qy + qz * qz);
    qw /= qn; qx /= qn; qy /= qn; qz /= qn;

    double R[3][3];
    R[0][0] = 1.0 - 2.0 * (qy * qy + qz * qz);
    R[0][1] = 2.0 * (qx * qy - qw * qz);
    R[0][2] = 2.0 * (qx * qz + qw * qy);
    R[1][0] = 2.0 * (qx * qy + qw * qz);
    R[1][1] = 1.0 - 2.0 * (qx * qx + qz * qz);
    R[1][2] = 2.0 * (qy * qz - qw * qx);
    R[2][0] = 2.0 * (qx * qz - qw * qy);
    R[2][1] = 2.0 * (qy * qz + qw * qx);
    R[2][2] = 1.0 - 2.0 * (qx * qx + qy * qy);

    // safeguard vs convention flip: objective is tr(R H); transpose if better
    double tr1 = 0.0, tr2 = 0.0;
    for (int i = 0; i < 3; ++i)
      for (int j = 0; j < 3; ++j) {
        tr1 += R[i][j] * H[j][i];
        tr2 += R[j][i] * H[j][i];
      }
    if (tr2 > tr1) {
      for (int i = 0; i < 3; ++i)
        for (int j = i + 1; j < 3; ++j) {
          double tmp = R[i][j]; R[i][j] = R[j][i]; R[j][i] = tmp;
        }
    }

    double tx = c2[0] - (R[0][0] * c1[0] + R[0][1] * c1[1] + R[0][2] * c1[2]);
    double ty = c2[1] - (R[1][0] * c1[0] + R[1][1] * c1[1] + R[1][2] * c1[2]);
    double tz = c2[2] - (R[2][0] * c1[0] + R[2][1] * c1[1] + R[2][2] * c1[2]);

    auto sgn = [](double x) { return x >= 0.0 ? 1.0 : -1.0; };
    double oqw = 0.5 * sqrt(fmax(1.0 + R[0][0] + R[1][1] + R[2][2], 1e-12));
    double oqx = 0.5 * sqrt(fmax(1.0 + R[0][0] - R[1][1] - R[2][2], 1e-12)) *
                 sgn(R[2][1] - R[1][2]);
    double oqy = 0.5 * sqrt(fmax(1.0 - R[0][0] + R[1][1] - R[2][2], 1e-12)) *
                 sgn(R[0][2] - R[2][0]);
    double oqz = 0.5 * sqrt(fmax(1.0 - R[0][0] - R[1][1] + R[2][2], 1e-12)) *
                 sgn(R[1][0] - R[0][1]);

    float* T = out + b * 16;
    T[0]  = (float)R[0][0]; T[1]  = (float)R[0][1]; T[2]  = (float)R[0][2]; T[3]  = (float)tx;
    T[4]  = (float)R[1][0]; T[5]  = (float)R[1][1]; T[6]  = (float)R[1][2]; T[7]  = (float)ty;
    T[8]  = (float)R[2][0]; T[9]  = (float)R[2][1]; T[10] = (float)R[2][2]; T[11] = (float)tz;
    T[12] = 0.f; T[13] = 0.f; T[14] = 0.f; T[15] = 1.f;
    float* Q = out + 128 + b * 4;
    Q[0] = (float)oqw; Q[1] = (float)oqx; Q[2] = (float)oqy; Q[3] = (float)oqz;
    float* Tt = out + 160 + b * 3;
    Tt[0] = (float)tx; Tt[1] = (float)ty; Tt[2] = (float)tz;
  }
}

// ---------------- launch ----------------
extern "C" void kernel_launch(void* const* d_in, const int* in_sizes, int n_in,
                              void* d_out, int out_size, void* d_ws, size_t ws_size,
                              hipStream_t stream) {
  const float* pc1 = (const float*)d_in[0];
  const float* pc2 = (const float*)d_in[1];
  float* out = (float*)d_out;
  char* ws = (char*)d_ws;

  float4* partA = (float4*)ws;
  float*  partM = (float*)(ws + OFF_PARTM);

  cpnet_partial<<<dim3(cN1 / 256, cMC, cB), 256, 0, stream>>>(pc1, pc2,
                                                              partA, partM);
  cpnet_finalize<<<cB, 512, 0, stream>>>(pc1, partA, partM, out);
}